// Round 8
// baseline (876.429 us; speedup 1.0000x reference)
//
#include <hip/hip_runtime.h>

#define N_NODES 253952   // = 992 * 256 = 248 * 1024 exactly
#define N_EDGES 4000000
#define N_GRAPHS 4096
#define NEG_SLOPE 0.01f

#define NB   248          // buckets (1024 nodes each)
#define CAP  20480        // staging capacity per bucket (mean 16129)
#define EPB  4096         // edges per partA block
#define NBIN 64           // degree bins for counting sort
#define WSCALE (1.0f / 16383.0f)

__device__ __forceinline__ float lrelu(float v) {
    return v > 0.0f ? v : v * NEG_SLOPE;
}

__device__ __forceinline__ unsigned short f2bf(float f) {   // RNE
    unsigned b = __float_as_uint(f);
    return (unsigned short)((b + 0x7FFF + ((b >> 16) & 1)) >> 16);
}

__device__ __forceinline__ void fma_bf16x8(float acc[8], const uint4 v, const float w) {
    acc[0] += __uint_as_float(v.x << 16) * w;
    acc[1] += __uint_as_float(v.x & 0xFFFF0000u) * w;
    acc[2] += __uint_as_float(v.y << 16) * w;
    acc[3] += __uint_as_float(v.y & 0xFFFF0000u) * w;
    acc[4] += __uint_as_float(v.z << 16) * w;
    acc[5] += __uint_as_float(v.z & 0xFFFF0000u) * w;
    acc[6] += __uint_as_float(v.w << 16) * w;
    acc[7] += __uint_as_float(v.w & 0xFFFF0000u) * w;
}

// ---------------- CSR build, pass A: bucket partition (x4 replicated counters) --
__global__ void partA_kernel(const int* __restrict__ src, const int* __restrict__ dst,
                             const float* __restrict__ ew,
                             int* __restrict__ bucket_cnt, int2* __restrict__ staging) {
    __shared__ int cnt[NB][4], base[NB][4], cur[NB][4];
    for (int i = threadIdx.x; i < NB * 4; i += 256) ((int*)cnt)[i] = 0;
    __syncthreads();
    const int e0 = blockIdx.x * EPB;
    const int r = threadIdx.x & 3;
    int s[16], d[16]; float w[16];
#pragma unroll
    for (int k = 0; k < 16; ++k) {
        int e = e0 + k * 256 + threadIdx.x;
        if (e < N_EDGES) { s[k] = src[e]; d[k] = dst[e]; w[k] = ew[e]; }
        else d[k] = -1;
    }
#pragma unroll
    for (int k = 0; k < 16; ++k)
        if (d[k] >= 0) atomicAdd(&cnt[d[k] >> 10][r], 1);
    __syncthreads();
    for (int i = threadIdx.x; i < NB; i += 256) {
#pragma unroll
        for (int rr = 0; rr < 4; ++rr) {
            int c = cnt[i][rr];
            base[i][rr] = (c > 0) ? atomicAdd(&bucket_cnt[i], c) : 0;
            cur[i][rr] = 0;
        }
    }
    __syncthreads();
#pragma unroll
    for (int k = 0; k < 16; ++k) {
        if (d[k] >= 0) {
            int b = d[k] >> 10;
            int off = atomicAdd(&cur[b][r], 1);
            staging[(size_t)b * CAP + base[b][r] + off] =
                make_int2(s[k] | ((d[k] & 1023) << 18), __float_as_int(w[k]));
        }
    }
}

__global__ void bucket_scan_kernel(const int* __restrict__ bucket_cnt,
                                   int* __restrict__ bucket_base,
                                   int* __restrict__ row_start) {
    __shared__ int s[256];
    int v = (threadIdx.x < NB) ? bucket_cnt[threadIdx.x] : 0;
    s[threadIdx.x] = v;
    __syncthreads();
    for (int off = 1; off < 256; off <<= 1) {
        int t = (threadIdx.x >= off) ? s[threadIdx.x - off] : 0;
        __syncthreads();
        s[threadIdx.x] += t;
        __syncthreads();
    }
    if (threadIdx.x < NB) bucket_base[threadIdx.x] = s[threadIdx.x] - v;
    if (threadIdx.x == 0) row_start[N_NODES] = N_EDGES;   // sentinel
}

// ---------------- CSR build, pass B: per-bucket counting sort ----------------
// Final CSR record packed to 4 B: src(18b) | wq(14b). Also emits deg[].
__global__ void partB_kernel(const int2* __restrict__ staging,
                             const int* __restrict__ bucket_cnt,
                             const int* __restrict__ bucket_base,
                             int* __restrict__ row_start, unsigned* __restrict__ csr,
                             int* __restrict__ deg) {
    __shared__ int hist[1024];
    __shared__ int scan_s[256];
    const int b = blockIdx.x;
    const int cnt = bucket_cnt[b];
    const int bbase = bucket_base[b];
    const int2* rec = staging + (size_t)b * CAP;
    for (int i = threadIdx.x; i < 1024; i += 256) hist[i] = 0;
    __syncthreads();
    for (int i = threadIdx.x; i < cnt; i += 256)
        atomicAdd(&hist[rec[i].x >> 18], 1);
    __syncthreads();
    const int t = threadIdx.x;
    int h0 = hist[4 * t], h1 = hist[4 * t + 1], h2 = hist[4 * t + 2], h3 = hist[4 * t + 3];
    int sum = h0 + h1 + h2 + h3;
    scan_s[t] = sum;
    __syncthreads();
    for (int off = 1; off < 256; off <<= 1) {
        int tv = (t >= off) ? scan_s[t - off] : 0;
        __syncthreads();
        scan_s[t] += tv;
        __syncthreads();
    }
    int excl = scan_s[t] - sum;
    int e0 = excl, e1 = excl + h0, e2 = excl + h0 + h1, e3 = excl + h0 + h1 + h2;
    int node0 = b * 1024 + 4 * t;
    row_start[node0]     = bbase + e0;
    row_start[node0 + 1] = bbase + e1;
    row_start[node0 + 2] = bbase + e2;
    row_start[node0 + 3] = bbase + e3;
    deg[node0] = h0; deg[node0 + 1] = h1; deg[node0 + 2] = h2; deg[node0 + 3] = h3;
    hist[4 * t] = e0; hist[4 * t + 1] = e1; hist[4 * t + 2] = e2; hist[4 * t + 3] = e3;
    __syncthreads();
    for (int i = threadIdx.x; i < cnt; i += 256) {
        int2 r = rec[i];
        int dl = r.x >> 18;
        int pos = bbase + atomicAdd(&hist[dl], 1);
        int wq = (int)(__int_as_float(r.y) * 16383.0f + 0.5f);
        wq = wq < 0 ? 0 : (wq > 16383 ? 16383 : wq);
        csr[pos] = (unsigned)(r.x & 0x3FFFF) | ((unsigned)wq << 18);
    }
}

// ---------------- Degree counting sort: hist -> scan -> place ----------------
__global__ void deg_count_kernel(const int* __restrict__ deg, int* __restrict__ bin_cnt) {
    __shared__ int lb[NBIN];
    if (threadIdx.x < NBIN) lb[threadIdx.x] = 0;
    __syncthreads();
    int i = blockIdx.x * 256 + threadIdx.x;
    int d = deg[i]; if (d > NBIN - 1) d = NBIN - 1;
    atomicAdd(&lb[d], 1);
    __syncthreads();
    if (threadIdx.x < NBIN && lb[threadIdx.x] > 0)
        atomicAdd(&bin_cnt[threadIdx.x], lb[threadIdx.x]);
}

__global__ void bin_scan_kernel(const int* __restrict__ bin_cnt, int* __restrict__ bin_base) {
    __shared__ int s[NBIN];
    int t = threadIdx.x;
    int v = bin_cnt[t];
    s[t] = v;
    __syncthreads();
    for (int off = 1; off < NBIN; off <<= 1) {
        int tv = (t >= off) ? s[t - off] : 0;
        __syncthreads();
        s[t] += tv;
        __syncthreads();
    }
    bin_base[t] = s[t] - v;   // exclusive; consumed as cursor by place_kernel
}

// place: perm/invperm + permuted row_start/row_end
__global__ void place_kernel(const int* __restrict__ deg, const int* __restrict__ row_start,
                             int* __restrict__ bin_base,
                             int* __restrict__ perm, int* __restrict__ invperm,
                             int* __restrict__ rs2, int* __restrict__ re2) {
    __shared__ int lcnt[NBIN], lbase[NBIN];
    if (threadIdx.x < NBIN) lcnt[threadIdx.x] = 0;
    __syncthreads();
    int i = blockIdx.x * 256 + threadIdx.x;
    int d = deg[i]; if (d > NBIN - 1) d = NBIN - 1;
    int myoff = atomicAdd(&lcnt[d], 1);
    __syncthreads();
    if (threadIdx.x < NBIN && lcnt[threadIdx.x] > 0)
        lbase[threadIdx.x] = atomicAdd(&bin_base[threadIdx.x], lcnt[threadIdx.x]);
    __syncthreads();
    int pos = lbase[d] + myoff;
    perm[pos] = i;
    invperm[i] = pos;
    rs2[pos] = row_start[i];
    re2[pos] = row_start[i + 1];
}

// Translate CSR src fields into permuted coordinates (in place).
__global__ void csr_translate_kernel(unsigned* __restrict__ csr, const int* __restrict__ invperm) {
    int i4 = (blockIdx.x * 256 + threadIdx.x) * 4;
    if (i4 + 3 >= N_EDGES) {
        for (int i = i4; i < N_EDGES; ++i) {
            unsigned r = csr[i];
            csr[i] = (unsigned)invperm[r & 0x3FFFFu] | (r & 0xFFFC0000u);
        }
        return;
    }
    uint4 r = *(uint4*)(csr + i4);
    r.x = (unsigned)invperm[r.x & 0x3FFFFu] | (r.x & 0xFFFC0000u);
    r.y = (unsigned)invperm[r.y & 0x3FFFFu] | (r.y & 0xFFFC0000u);
    r.z = (unsigned)invperm[r.z & 0x3FFFFu] | (r.z & 0xFFFC0000u);
    r.w = (unsigned)invperm[r.w & 0x3FFFFu] | (r.w & 0xFFFC0000u);
    *(uint4*)(csr + i4) = r;
}

// Pad + convert x [N,6] f32 -> xb [N,8] bf16 in PERMUTED order.
__global__ void pad_x_kernel(const float* __restrict__ x, const int* __restrict__ perm,
                             unsigned short* __restrict__ xb) {
    int i = blockIdx.x * 256 + threadIdx.x;
    if (i >= N_NODES * 8) return;
    int k = i >> 3, j = i & 7;
    int n = perm[k];
    xb[i] = (j < 6) ? f2bf(x[n * 6 + j]) : (unsigned short)0;
}

// ---------------- Fused GCN layer (UNCHANGED from R7) ------------------------
template <int WPAD, int WIN, int WOUT, bool DBL, bool OUT_F32>
__global__ void gcn_layer_kernel(const unsigned short* __restrict__ xb,
                                 const unsigned* __restrict__ csr,
                                 const int* __restrict__ row_start, const int* __restrict__ row_end,
                                 const float* __restrict__ Wg, const float* __restrict__ bg,
                                 void* __restrict__ hout) {
    constexpr int LPN = WPAD / 8;
    constexpr int GROUPS = 256 / LPN;
    __shared__ float rows[GROUPS][WPAD + 4];   // +4: break 32-bank stride
    int g = threadIdx.x / LPN;
    int j = threadIdx.x % LPN;
    int node = blockIdx.x * GROUPS + g;   // N_NODES % GROUPS == 0
    float acc[8] = {0.f, 0.f, 0.f, 0.f, 0.f, 0.f, 0.f, 0.f};
    int e = row_start[node];
    int end = row_end[node];
    const uint4* xv = (const uint4*)xb;
    for (; e + 4 <= end; e += 4) {
        unsigned r0 = csr[e];
        unsigned r1 = csr[e + 1];
        unsigned r2 = csr[e + 2];
        unsigned r3 = csr[e + 3];
        uint4 v0 = xv[(size_t)(r0 & 0x3FFFFu) * LPN + j];
        uint4 v1 = xv[(size_t)(r1 & 0x3FFFFu) * LPN + j];
        uint4 v2 = xv[(size_t)(r2 & 0x3FFFFu) * LPN + j];
        uint4 v3 = xv[(size_t)(r3 & 0x3FFFFu) * LPN + j];
        fma_bf16x8(acc, v0, (float)(r0 >> 18) * WSCALE);
        fma_bf16x8(acc, v1, (float)(r1 >> 18) * WSCALE);
        fma_bf16x8(acc, v2, (float)(r2 >> 18) * WSCALE);
        fma_bf16x8(acc, v3, (float)(r3 >> 18) * WSCALE);
    }
    for (; e < end; ++e) {
        unsigned r = csr[e];
        uint4 v = xv[(size_t)(r & 0x3FFFFu) * LPN + j];
        fma_bf16x8(acc, v, (float)(r >> 18) * WSCALE);
    }
#pragma unroll
    for (int i = 0; i < 8; ++i) rows[g][8 * j + i] = acc[i];
    __syncthreads();
    for (int idx = threadIdx.x; idx < GROUPS * WOUT; idx += 256) {
        int g2 = idx / WOUT;
        int j2 = idx - g2 * WOUT;
        int node2 = blockIdx.x * GROUPS + g2;
        float a = bg[j2];
#pragma unroll
        for (int k = 0; k < WIN; ++k) a += rows[g2][k] * Wg[k * WOUT + j2];
        a = lrelu(a);
        if (DBL) a = lrelu(a);
        if (OUT_F32) ((float*)hout)[(size_t)node2 * WOUT + j2] = a;
        else ((unsigned short*)hout)[(size_t)node2 * WOUT + j2] = f2bf(a);
    }
}

// ---------------- Pool (batch sorted; h4 stored in permuted order) -----------
__global__ void pool_kernel(const float* __restrict__ h,
                            const int* __restrict__ batch,
                            const int* __restrict__ invperm,
                            float* __restrict__ pooled) {
    int g = blockIdx.x;
    __shared__ int s_start, s_end;
    if (threadIdx.x == 0) {
        int lo = 0, hi = N_NODES;
        while (lo < hi) { int m = (lo + hi) >> 1; if (batch[m] < g) lo = m + 1; else hi = m; }
        s_start = lo;
        lo = 0; hi = N_NODES;
        while (lo < hi) { int m = (lo + hi) >> 1; if (batch[m] < g + 1) lo = m + 1; else hi = m; }
        s_end = lo;
    }
    __syncthreads();
    int j = threadIdx.x;
    if (j < 50) {
        float acc = 0.0f;
        for (int i = s_start; i < s_end; ++i) acc += h[(size_t)invperm[i] * 50 + j];
        pooled[g * 50 + j] = acc;
    }
}

// ---------------- Final MLP ----------------
__global__ void mlp_kernel(const float* __restrict__ pooled,
                           const float* __restrict__ Wf1, const float* __restrict__ bf1,
                           const float* __restrict__ Wf2, const float* __restrict__ bf2,
                           const float* __restrict__ Wf3, const float* __restrict__ bf3,
                           float* __restrict__ out) {
    __shared__ float W1s[50 * 30], b1s[30];
    __shared__ float W2s[30 * 20], b2s[20];
    __shared__ float W3s[20 * 2], b3s[2];
    for (int i = threadIdx.x; i < 50 * 30; i += blockDim.x) W1s[i] = Wf1[i];
    for (int i = threadIdx.x; i < 30; i += blockDim.x) b1s[i] = bf1[i];
    for (int i = threadIdx.x; i < 30 * 20; i += blockDim.x) W2s[i] = Wf2[i];
    for (int i = threadIdx.x; i < 20; i += blockDim.x) b2s[i] = bf2[i];
    for (int i = threadIdx.x; i < 20 * 2; i += blockDim.x) W3s[i] = Wf3[i];
    for (int i = threadIdx.x; i < 2; i += blockDim.x) b3s[i] = bf3[i];
    __syncthreads();
    int g = blockIdx.x * blockDim.x + threadIdx.x;
    if (g >= N_GRAPHS) return;
    float in[50];
#pragma unroll
    for (int k = 0; k < 50; ++k) in[k] = pooled[g * 50 + k];
    float t1[30];
#pragma unroll
    for (int j = 0; j < 30; ++j) {
        float a = b1s[j];
#pragma unroll
        for (int k = 0; k < 50; ++k) a += in[k] * W1s[k * 30 + j];
        t1[j] = lrelu(a);
    }
    float t2[20];
#pragma unroll
    for (int j = 0; j < 20; ++j) {
        float a = b2s[j];
#pragma unroll
        for (int k = 0; k < 30; ++k) a += t1[k] * W2s[k * 20 + j];
        t2[j] = lrelu(a);
    }
#pragma unroll
    for (int j = 0; j < 2; ++j) {
        float a = b3s[j];
#pragma unroll
        for (int k = 0; k < 20; ++k) a += t2[k] * W3s[k * 2 + j];
        out[g * 2 + j] = lrelu(a);
    }
}

extern "C" void kernel_launch(void* const* d_in, const int* in_sizes, int n_in,
                              void* d_out, int out_size, void* d_ws, size_t ws_size,
                              hipStream_t stream) {
    const float* x     = (const float*)d_in[0];
    const int*   ei    = (const int*)d_in[1];
    const float* ew    = (const float*)d_in[2];
    const int*   batch = (const int*)d_in[3];
    const float* W1 = (const float*)d_in[4];
    const float* b1 = (const float*)d_in[5];
    const float* W2 = (const float*)d_in[6];
    const float* b2 = (const float*)d_in[7];
    const float* W3 = (const float*)d_in[8];
    const float* b3 = (const float*)d_in[9];
    const float* W4 = (const float*)d_in[10];
    const float* b4 = (const float*)d_in[11];
    const float* Wf1 = (const float*)d_in[12];
    const float* bf1 = (const float*)d_in[13];
    const float* Wf2 = (const float*)d_in[14];
    const float* bf2 = (const float*)d_in[15];
    const float* Wf3 = (const float*)d_in[16];
    const float* bf3 = (const float*)d_in[17];

    const int* src = ei;            // edge_index[0]
    const int* dst = ei + N_EDGES;  // edge_index[1]
    float* out = (float*)d_out;

    // Workspace:
    //   csr       : E uint (16 MB, packed src'|wq — src' in permuted coords)
    //   bufA      : N*64*4 B — staging (NB*CAP int2 = 40.6 MB) overlays during build,
    //               then h1 [N,16]bf16 / h3 [N,64]bf16   (all node-major PERMUTED)
    //   bufB      : N*50*4 B — xb [N,8]bf16 front, then h2 [N,32]bf16, then h4 [N,50]f32
    //   row_start : N+1 ints (original order)
    //   deg/perm/invperm/rs2/re2 : N ints each
    //   bucket_cnt/base : NB ints; bin_cnt/bin_base : NBIN ints
    //   pooled    : 4096*50 f32
    char* wsp = (char*)d_ws;
    unsigned* csr     = (unsigned*)wsp;  wsp += (size_t)N_EDGES * 4;
    char*  bufA       = wsp;             wsp += (size_t)N_NODES * 64 * 4;
    char*  bufB       = wsp;             wsp += (size_t)N_NODES * 50 * 4;
    int*   row_start  = (int*)wsp;       wsp += (size_t)(N_NODES + 1) * 4;
    int*   deg        = (int*)wsp;       wsp += (size_t)N_NODES * 4;
    int*   perm       = (int*)wsp;       wsp += (size_t)N_NODES * 4;
    int*   invperm    = (int*)wsp;       wsp += (size_t)N_NODES * 4;
    int*   rs2        = (int*)wsp;       wsp += (size_t)N_NODES * 4;
    int*   re2        = (int*)wsp;       wsp += (size_t)N_NODES * 4;
    int*   bucket_cnt = (int*)wsp;       wsp += NB * 4;
    int*   bucket_base= (int*)wsp;       wsp += NB * 4;
    int*   bin_cnt    = (int*)wsp;       wsp += NBIN * 4;
    int*   bin_base   = (int*)wsp;       wsp += NBIN * 4;
    float* pooled     = (float*)wsp;

    int2*           staging = (int2*)bufA;            // build-time only
    unsigned short* xb      = (unsigned short*)bufB;  // [N,8] bf16 permuted
    unsigned short* h1      = (unsigned short*)bufA;  // [N,16]
    unsigned short* h2      = (unsigned short*)(bufB + (size_t)N_NODES * 8 * 2); // [N,32]
    unsigned short* h3      = (unsigned short*)bufA;  // [N,64]
    float*          h4      = (float*)bufB;           // [N,50] f32

    const int BS = 256;
    const int NBLK = N_NODES / 256;               // 992
    const int ABLK = (N_EDGES + EPB - 1) / EPB;   // 977

    // ---- CSR build (bucketed two-pass) ----
    hipMemsetAsync(bucket_cnt, 0, (NB * 2 + NBIN * 2) * 4, stream);  // cnt/base/bin_cnt/bin_base contiguous
    partA_kernel<<<ABLK, BS, 0, stream>>>(src, dst, ew, bucket_cnt, staging);
    bucket_scan_kernel<<<1, BS, 0, stream>>>(bucket_cnt, bucket_base, row_start);
    partB_kernel<<<NB, BS, 0, stream>>>(staging, bucket_cnt, bucket_base, row_start, csr, deg);

    // ---- degree counting sort -> perm/invperm, permuted rows; translate CSR ----
    deg_count_kernel<<<NBLK, BS, 0, stream>>>(deg, bin_cnt);
    bin_scan_kernel<<<1, NBIN, 0, stream>>>(bin_cnt, bin_base);
    place_kernel<<<NBLK, BS, 0, stream>>>(deg, row_start, bin_base, perm, invperm, rs2, re2);
    csr_translate_kernel<<<(N_EDGES / 4 + 255) / 256, BS, 0, stream>>>(csr, invperm);
    pad_x_kernel<<<(N_NODES * 8 + 255) / 256, BS, 0, stream>>>(x, perm, xb);

    // ---- 4 fused GCN layers (bf16 features, fp32 accumulate; degree-sorted) ----
    gcn_layer_kernel<8, 6, 16, false, false><<<N_NODES / 256, BS, 0, stream>>>(
        xb, csr, rs2, re2, W1, b1, h1);
    gcn_layer_kernel<16, 16, 32, false, false><<<N_NODES / 128, BS, 0, stream>>>(
        h1, csr, rs2, re2, W2, b2, h2);
    gcn_layer_kernel<32, 32, 64, false, false><<<N_NODES / 64, BS, 0, stream>>>(
        h2, csr, rs2, re2, W3, b3, h3);
    gcn_layer_kernel<64, 64, 50, true, true><<<N_NODES / 32, BS, 0, stream>>>(
        h3, csr, rs2, re2, W4, b4, h4);

    // ---- Pool + MLP ----
    pool_kernel<<<N_GRAPHS, 64, 0, stream>>>(h4, batch, invperm, pooled);
    mlp_kernel<<<(N_GRAPHS + 255) / 256, 256, 0, stream>>>(pooled, Wf1, bf1, Wf2, bf2, Wf3, bf3, out);
}

// Round 9
// 800.720 us; speedup vs baseline: 1.0946x; 1.0946x over previous
//
#include <hip/hip_runtime.h>

#define N_NODES 253952   // = 992 * 256 = 248 * 1024 exactly
#define N_EDGES 4000000
#define N_GRAPHS 4096
#define NEG_SLOPE 0.01f

#define NB   248          // buckets (1024 nodes each)
#define CAP  20480        // staging capacity per bucket (mean 16129)
#define EPB  4096         // edges per partA block
#define WSCALE (1.0f / 16383.0f)

__device__ __forceinline__ float lrelu(float v) {
    return v > 0.0f ? v : v * NEG_SLOPE;
}

__device__ __forceinline__ unsigned short f2bf(float f) {   // RNE
    unsigned b = __float_as_uint(f);
    return (unsigned short)((b + 0x7FFF + ((b >> 16) & 1)) >> 16);
}

__device__ __forceinline__ void fma_bf16x8(float acc[8], const uint4 v, const float w) {
    acc[0] += __uint_as_float(v.x << 16) * w;
    acc[1] += __uint_as_float(v.x & 0xFFFF0000u) * w;
    acc[2] += __uint_as_float(v.y << 16) * w;
    acc[3] += __uint_as_float(v.y & 0xFFFF0000u) * w;
    acc[4] += __uint_as_float(v.z << 16) * w;
    acc[5] += __uint_as_float(v.z & 0xFFFF0000u) * w;
    acc[6] += __uint_as_float(v.w << 16) * w;
    acc[7] += __uint_as_float(v.w & 0xFFFF0000u) * w;
}

// ---------------- CSR build, pass A: bucket partition (x4 replicated counters) --
__global__ void partA_kernel(const int* __restrict__ src, const int* __restrict__ dst,
                             const float* __restrict__ ew,
                             int* __restrict__ bucket_cnt, int2* __restrict__ staging) {
    __shared__ int cnt[NB][4], base[NB][4], cur[NB][4];
    for (int i = threadIdx.x; i < NB * 4; i += 256) ((int*)cnt)[i] = 0;
    __syncthreads();
    const int e0 = blockIdx.x * EPB;
    const int r = threadIdx.x & 3;
    int s[16], d[16]; float w[16];
#pragma unroll
    for (int k = 0; k < 16; ++k) {
        int e = e0 + k * 256 + threadIdx.x;
        if (e < N_EDGES) { s[k] = src[e]; d[k] = dst[e]; w[k] = ew[e]; }
        else d[k] = -1;
    }
#pragma unroll
    for (int k = 0; k < 16; ++k)
        if (d[k] >= 0) atomicAdd(&cnt[d[k] >> 10][r], 1);
    __syncthreads();
    for (int i = threadIdx.x; i < NB; i += 256) {
#pragma unroll
        for (int rr = 0; rr < 4; ++rr) {
            int c = cnt[i][rr];
            base[i][rr] = (c > 0) ? atomicAdd(&bucket_cnt[i], c) : 0;
            cur[i][rr] = 0;
        }
    }
    __syncthreads();
#pragma unroll
    for (int k = 0; k < 16; ++k) {
        if (d[k] >= 0) {
            int b = d[k] >> 10;
            int off = atomicAdd(&cur[b][r], 1);
            staging[(size_t)b * CAP + base[b][r] + off] =
                make_int2(s[k] | ((d[k] & 1023) << 18), __float_as_int(w[k]));
        }
    }
}

__global__ void bucket_scan_kernel(const int* __restrict__ bucket_cnt,
                                   int* __restrict__ bucket_base,
                                   int* __restrict__ row_start) {
    __shared__ int s[256];
    int v = (threadIdx.x < NB) ? bucket_cnt[threadIdx.x] : 0;
    s[threadIdx.x] = v;
    __syncthreads();
    for (int off = 1; off < 256; off <<= 1) {
        int t = (threadIdx.x >= off) ? s[threadIdx.x - off] : 0;
        __syncthreads();
        s[threadIdx.x] += t;
        __syncthreads();
    }
    if (threadIdx.x < NB) bucket_base[threadIdx.x] = s[threadIdx.x] - v;
    if (threadIdx.x == 0) row_start[N_NODES] = N_EDGES;   // sentinel
}

// ---------------- CSR build, pass B: per-bucket counting sort ----------------
// Final CSR record packed to 4 B: src(18b) | wq(14b), wq = round(w*16383).
__global__ void partB_kernel(const int2* __restrict__ staging,
                             const int* __restrict__ bucket_cnt,
                             const int* __restrict__ bucket_base,
                             int* __restrict__ row_start, unsigned* __restrict__ csr) {
    __shared__ int hist[1024];
    __shared__ int scan_s[256];
    const int b = blockIdx.x;
    const int cnt = bucket_cnt[b];
    const int bbase = bucket_base[b];
    const int2* rec = staging + (size_t)b * CAP;
    for (int i = threadIdx.x; i < 1024; i += 256) hist[i] = 0;
    __syncthreads();
    for (int i = threadIdx.x; i < cnt; i += 256)
        atomicAdd(&hist[rec[i].x >> 18], 1);
    __syncthreads();
    const int t = threadIdx.x;
    int h0 = hist[4 * t], h1 = hist[4 * t + 1], h2 = hist[4 * t + 2], h3 = hist[4 * t + 3];
    int sum = h0 + h1 + h2 + h3;
    scan_s[t] = sum;
    __syncthreads();
    for (int off = 1; off < 256; off <<= 1) {
        int tv = (t >= off) ? scan_s[t - off] : 0;
        __syncthreads();
        scan_s[t] += tv;
        __syncthreads();
    }
    int excl = scan_s[t] - sum;
    int e0 = excl, e1 = excl + h0, e2 = excl + h0 + h1, e3 = excl + h0 + h1 + h2;
    int node0 = b * 1024 + 4 * t;
    row_start[node0]     = bbase + e0;
    row_start[node0 + 1] = bbase + e1;
    row_start[node0 + 2] = bbase + e2;
    row_start[node0 + 3] = bbase + e3;
    hist[4 * t] = e0; hist[4 * t + 1] = e1; hist[4 * t + 2] = e2; hist[4 * t + 3] = e3;
    __syncthreads();
    for (int i = threadIdx.x; i < cnt; i += 256) {
        int2 r = rec[i];
        int dl = r.x >> 18;
        int pos = bbase + atomicAdd(&hist[dl], 1);
        int wq = (int)(__int_as_float(r.y) * 16383.0f + 0.5f);
        wq = wq < 0 ? 0 : (wq > 16383 ? 16383 : wq);
        csr[pos] = (unsigned)(r.x & 0x3FFFF) | ((unsigned)wq << 18);
    }
}

// Pad + convert x [N,6] f32 -> xb [N,8] bf16 (zeros in 6,7).
__global__ void pad_x_kernel(const float* __restrict__ x, unsigned short* __restrict__ xb) {
    int i = blockIdx.x * 256 + threadIdx.x;
    if (i >= N_NODES * 8) return;
    int n = i >> 3, j = i & 7;
    xb[i] = (j < 6) ? f2bf(x[n * 6 + j]) : (unsigned short)0;
}

// ---------------- Fused GCN layer: dual-stream bf16 CSR gather + linear ------
// Each node's edge list is split in two halves processed as independent
// 4-batch streams in the same loop iteration -> 8 gathers in flight per group.
template <int WPAD, int WIN, int WOUT, bool DBL, bool OUT_F32>
__global__ void gcn_layer_kernel(const unsigned short* __restrict__ xb,
                                 const unsigned* __restrict__ csr,
                                 const int* __restrict__ row_start, const int* __restrict__ row_end,
                                 const float* __restrict__ Wg, const float* __restrict__ bg,
                                 void* __restrict__ hout) {
    constexpr int LPN = WPAD / 8;
    constexpr int GROUPS = 256 / LPN;
    __shared__ float rows[GROUPS][WPAD + 4];   // +4: break 32-bank stride
    int g = threadIdx.x / LPN;
    int j = threadIdx.x % LPN;
    int node = blockIdx.x * GROUPS + g;   // N_NODES % GROUPS == 0
    float acc[8] = {0.f, 0.f, 0.f, 0.f, 0.f, 0.f, 0.f, 0.f};
    const int rs = row_start[node];
    const int re = row_end[node];
    const int d = re - rs;
    const int nbt = d >> 2;              // full 4-batches
    const int nb1 = (nbt + 1) >> 1;      // stream-1 gets the extra batch
    const uint4* xv = (const uint4*)xb;
    int e1 = rs;
    const int end1 = rs + 4 * nb1;
    int e2 = end1;
    const int end2b = rs + 4 * nbt;      // stream-2 batch end
    for (; e1 < end1; e1 += 4, e2 += 4) {
        unsigned rA0 = csr[e1], rA1 = csr[e1 + 1], rA2 = csr[e1 + 2], rA3 = csr[e1 + 3];
        const bool s2 = e2 < end2b;
        unsigned rB0 = 0, rB1 = 0, rB2 = 0, rB3 = 0;
        if (s2) { rB0 = csr[e2]; rB1 = csr[e2 + 1]; rB2 = csr[e2 + 2]; rB3 = csr[e2 + 3]; }
        uint4 vA0 = xv[(size_t)(rA0 & 0x3FFFFu) * LPN + j];
        uint4 vA1 = xv[(size_t)(rA1 & 0x3FFFFu) * LPN + j];
        uint4 vA2 = xv[(size_t)(rA2 & 0x3FFFFu) * LPN + j];
        uint4 vA3 = xv[(size_t)(rA3 & 0x3FFFFu) * LPN + j];
        uint4 vB0, vB1, vB2, vB3;
        if (s2) {
            vB0 = xv[(size_t)(rB0 & 0x3FFFFu) * LPN + j];
            vB1 = xv[(size_t)(rB1 & 0x3FFFFu) * LPN + j];
            vB2 = xv[(size_t)(rB2 & 0x3FFFFu) * LPN + j];
            vB3 = xv[(size_t)(rB3 & 0x3FFFFu) * LPN + j];
        }
        fma_bf16x8(acc, vA0, (float)(rA0 >> 18) * WSCALE);
        fma_bf16x8(acc, vA1, (float)(rA1 >> 18) * WSCALE);
        fma_bf16x8(acc, vA2, (float)(rA2 >> 18) * WSCALE);
        fma_bf16x8(acc, vA3, (float)(rA3 >> 18) * WSCALE);
        if (s2) {
            fma_bf16x8(acc, vB0, (float)(rB0 >> 18) * WSCALE);
            fma_bf16x8(acc, vB1, (float)(rB1 >> 18) * WSCALE);
            fma_bf16x8(acc, vB2, (float)(rB2 >> 18) * WSCALE);
            fma_bf16x8(acc, vB3, (float)(rB3 >> 18) * WSCALE);
        }
    }
    for (int e = end2b; e < re; ++e) {   // <=3 scalar remainder edges
        unsigned r = csr[e];
        uint4 v = xv[(size_t)(r & 0x3FFFFu) * LPN + j];
        fma_bf16x8(acc, v, (float)(r >> 18) * WSCALE);
    }
#pragma unroll
    for (int i = 0; i < 8; ++i) rows[g][8 * j + i] = acc[i];
    __syncthreads();
    for (int idx = threadIdx.x; idx < GROUPS * WOUT; idx += 256) {
        int g2 = idx / WOUT;
        int j2 = idx - g2 * WOUT;
        int node2 = blockIdx.x * GROUPS + g2;
        float a = bg[j2];
#pragma unroll
        for (int k = 0; k < WIN; ++k) a += rows[g2][k] * Wg[k * WOUT + j2];
        a = lrelu(a);
        if (DBL) a = lrelu(a);
        if (OUT_F32) ((float*)hout)[(size_t)node2 * WOUT + j2] = a;
        else ((unsigned short*)hout)[(size_t)node2 * WOUT + j2] = f2bf(a);
    }
}

// ---------------- Pool (batch sorted -> binary search range) ----------------
__global__ void pool_kernel(const float* __restrict__ h,
                            const int* __restrict__ batch,
                            float* __restrict__ pooled) {
    int g = blockIdx.x;
    __shared__ int s_start, s_end;
    if (threadIdx.x == 0) {
        int lo = 0, hi = N_NODES;
        while (lo < hi) { int m = (lo + hi) >> 1; if (batch[m] < g) lo = m + 1; else hi = m; }
        s_start = lo;
        lo = 0; hi = N_NODES;
        while (lo < hi) { int m = (lo + hi) >> 1; if (batch[m] < g + 1) lo = m + 1; else hi = m; }
        s_end = lo;
    }
    __syncthreads();
    int j = threadIdx.x;
    if (j < 50) {
        float acc = 0.0f;
        for (int i = s_start; i < s_end; ++i) acc += h[(size_t)i * 50 + j];
        pooled[g * 50 + j] = acc;
    }
}

// ---------------- Final MLP ----------------
__global__ void mlp_kernel(const float* __restrict__ pooled,
                           const float* __restrict__ Wf1, const float* __restrict__ bf1,
                           const float* __restrict__ Wf2, const float* __restrict__ bf2,
                           const float* __restrict__ Wf3, const float* __restrict__ bf3,
                           float* __restrict__ out) {
    __shared__ float W1s[50 * 30], b1s[30];
    __shared__ float W2s[30 * 20], b2s[20];
    __shared__ float W3s[20 * 2], b3s[2];
    for (int i = threadIdx.x; i < 50 * 30; i += blockDim.x) W1s[i] = Wf1[i];
    for (int i = threadIdx.x; i < 30; i += blockDim.x) b1s[i] = bf1[i];
    for (int i = threadIdx.x; i < 30 * 20; i += blockDim.x) W2s[i] = Wf2[i];
    for (int i = threadIdx.x; i < 20; i += blockDim.x) b2s[i] = bf2[i];
    for (int i = threadIdx.x; i < 20 * 2; i += blockDim.x) W3s[i] = Wf3[i];
    for (int i = threadIdx.x; i < 2; i += blockDim.x) b3s[i] = bf3[i];
    __syncthreads();
    int g = blockIdx.x * blockDim.x + threadIdx.x;
    if (g >= N_GRAPHS) return;
    float in[50];
#pragma unroll
    for (int k = 0; k < 50; ++k) in[k] = pooled[g * 50 + k];
    float t1[30];
#pragma unroll
    for (int j = 0; j < 30; ++j) {
        float a = b1s[j];
#pragma unroll
        for (int k = 0; k < 50; ++k) a += in[k] * W1s[k * 30 + j];
        t1[j] = lrelu(a);
    }
    float t2[20];
#pragma unroll
    for (int j = 0; j < 20; ++j) {
        float a = b2s[j];
#pragma unroll
        for (int k = 0; k < 30; ++k) a += t1[k] * W2s[k * 20 + j];
        t2[j] = lrelu(a);
    }
#pragma unroll
    for (int j = 0; j < 2; ++j) {
        float a = b3s[j];
#pragma unroll
        for (int k = 0; k < 20; ++k) a += t2[k] * W3s[k * 2 + j];
        out[g * 2 + j] = lrelu(a);
    }
}

extern "C" void kernel_launch(void* const* d_in, const int* in_sizes, int n_in,
                              void* d_out, int out_size, void* d_ws, size_t ws_size,
                              hipStream_t stream) {
    const float* x     = (const float*)d_in[0];
    const int*   ei    = (const int*)d_in[1];
    const float* ew    = (const float*)d_in[2];
    const int*   batch = (const int*)d_in[3];
    const float* W1 = (const float*)d_in[4];
    const float* b1 = (const float*)d_in[5];
    const float* W2 = (const float*)d_in[6];
    const float* b2 = (const float*)d_in[7];
    const float* W3 = (const float*)d_in[8];
    const float* b3 = (const float*)d_in[9];
    const float* W4 = (const float*)d_in[10];
    const float* b4 = (const float*)d_in[11];
    const float* Wf1 = (const float*)d_in[12];
    const float* bf1 = (const float*)d_in[13];
    const float* Wf2 = (const float*)d_in[14];
    const float* bf2 = (const float*)d_in[15];
    const float* Wf3 = (const float*)d_in[16];
    const float* bf3 = (const float*)d_in[17];

    const int* src = ei;            // edge_index[0]
    const int* dst = ei + N_EDGES;  // edge_index[1]
    float* out = (float*)d_out;

    // Workspace (R7 layout):
    //   csr        : E uint (16 MB, packed src|wq)
    //   bufA       : N*64*4 B — staging (NB*CAP int2 = 40.6 MB) overlays during build,
    //                then h1 [N,16]bf16 / h3 [N,64]bf16
    //   bufB       : N*50*4 B — xb [N,8]bf16 front during build/L1,
    //                then h2 [N,32]bf16, then h4 [N,50]f32
    //   row_start  : N+1 ints
    //   bucket_cnt/base : NB ints each
    //   pooled     : 4096*50 f32
    char* wsp = (char*)d_ws;
    unsigned* csr     = (unsigned*)wsp;  wsp += (size_t)N_EDGES * 4;
    char*  bufA       = wsp;             wsp += (size_t)N_NODES * 64 * 4;
    char*  bufB       = wsp;             wsp += (size_t)N_NODES * 50 * 4;
    int*   row_start  = (int*)wsp;       wsp += (size_t)(N_NODES + 1) * 4;
    int*   bucket_cnt = (int*)wsp;       wsp += NB * 4;
    int*   bucket_base= (int*)wsp;       wsp += NB * 4;
    float* pooled     = (float*)wsp;

    int2*           staging = (int2*)bufA;            // build-time only
    unsigned short* xb      = (unsigned short*)bufB;  // [N,8] bf16
    unsigned short* h1      = (unsigned short*)bufA;  // [N,16]
    unsigned short* h2      = (unsigned short*)(bufB + (size_t)N_NODES * 8 * 2); // [N,32]
    unsigned short* h3      = (unsigned short*)bufA;  // [N,64]
    float*          h4      = (float*)bufB;           // [N,50] f32

    const int BS = 256;
    const int ABLK = (N_EDGES + EPB - 1) / EPB;   // 977

    // ---- CSR build (bucketed two-pass) + x pad/convert ----
    hipMemsetAsync(bucket_cnt, 0, NB * 4, stream);
    pad_x_kernel<<<(N_NODES * 8 + 255) / 256, BS, 0, stream>>>(x, xb);
    partA_kernel<<<ABLK, BS, 0, stream>>>(src, dst, ew, bucket_cnt, staging);
    bucket_scan_kernel<<<1, BS, 0, stream>>>(bucket_cnt, bucket_base, row_start);
    partB_kernel<<<NB, BS, 0, stream>>>(staging, bucket_cnt, bucket_base, row_start, csr);

    // ---- 4 fused GCN layers (bf16 features, fp32 accumulate, dual-stream) ----
    gcn_layer_kernel<8, 6, 16, false, false><<<N_NODES / 256, BS, 0, stream>>>(
        xb, csr, row_start, row_start + 1, W1, b1, h1);
    gcn_layer_kernel<16, 16, 32, false, false><<<N_NODES / 128, BS, 0, stream>>>(
        h1, csr, row_start, row_start + 1, W2, b2, h2);
    gcn_layer_kernel<32, 32, 64, false, false><<<N_NODES / 64, BS, 0, stream>>>(
        h2, csr, row_start, row_start + 1, W3, b3, h3);
    gcn_layer_kernel<64, 64, 50, true, true><<<N_NODES / 32, BS, 0, stream>>>(
        h3, csr, row_start, row_start + 1, W4, b4, h4);

    // ---- Pool + MLP ----
    pool_kernel<<<N_GRAPHS, 64, 0, stream>>>(h4, batch, pooled);
    mlp_kernel<<<(N_GRAPHS + 255) / 256, 256, 0, stream>>>(pooled, Wf1, bf1, Wf2, bf2, Wf3, bf3, out);
}